// Round 1
// 3917.052 us; speedup vs baseline: 3.4966x; 3.4966x over previous
//
#include <hip/hip_runtime.h>

typedef unsigned short u16;
typedef unsigned int u32;
typedef __bf16 bf16x8_t __attribute__((ext_vector_type(8)));
typedef float f32x4_t __attribute__((ext_vector_type(4)));

#define D_MODEL 1024
#define NHEAD   16
#define HSZ     64
#define T_SEQ   1024
#define BATCH   4
#define NROWS   4096   // B*T
#define DFF     4096
#define DCAT    1088   // D + Db
#define DB      64
#define VOCAB   32000
#define NLAYER  6

__device__ __forceinline__ float bf2f(u16 u) {
    union { float f; u32 i; } x; x.i = ((u32)u) << 16; return x.f;
}
__device__ __forceinline__ u16 f2bf(float f) {
    union { float f; u32 i; } x; x.f = f;
    u32 r = x.i + 0x7FFFu + ((x.i >> 16) & 1u);
    return (u16)(r >> 16);
}

// ---------------------------------------------------------------------------
// Transpose + f32->bf16: in [K,N] f32 -> out [N,K] bf16. blockIdx.z = matrix.
// ---------------------------------------------------------------------------
__global__ __launch_bounds__(256)
void transpose_cvt(const float* __restrict__ in, u16* __restrict__ out, int K, int N)
{
    __shared__ u16 tile[32][33];
    size_t moff = (size_t)blockIdx.z * K * N;
    in += moff; out += moff;
    int n0 = blockIdx.x * 32, k0 = blockIdx.y * 32;
    int tx = threadIdx.x & 31, ty = threadIdx.x >> 5; // 8 row-groups
    #pragma unroll
    for (int r = ty; r < 32; r += 8)
        tile[r][tx] = f2bf(in[(size_t)(k0 + r) * N + n0 + tx]);
    __syncthreads();
    #pragma unroll
    for (int r = ty; r < 32; r += 8)
        out[(size_t)(n0 + r) * K + k0 + tx] = tile[tx][r];
}

// ---------------------------------------------------------------------------
// Embedding: x[b,t,:] = tok[idx[b,t]] + pos[t]; also zeroes the loss slot.
// ---------------------------------------------------------------------------
__global__ __launch_bounds__(256)
void embed_kernel(const int* __restrict__ idx, const float* __restrict__ tok,
                  const float* __restrict__ pos, float* __restrict__ x,
                  float* __restrict__ loss_slot)
{
    int row = blockIdx.x, tid = threadIdx.x;
    if (row == 0 && tid == 0) *loss_slot = 0.f;
    int token = idx[row];
    float4 a = reinterpret_cast<const float4*>(tok + (size_t)token * D_MODEL)[tid];
    float4 b = reinterpret_cast<const float4*>(pos + (size_t)(row & (T_SEQ - 1)) * D_MODEL)[tid];
    float4 r; r.x = a.x + b.x; r.y = a.y + b.y; r.z = a.z + b.z; r.w = a.w + b.w;
    reinterpret_cast<float4*>(x + (size_t)row * D_MODEL)[tid] = r;
}

// ---------------------------------------------------------------------------
// LayerNorm over D=1024, one row per block (256 thr * float4).
// WITH_BOOK: also fill out[:,1024:1088] with book_table[ibx[b]] (bf16).
// ---------------------------------------------------------------------------
template<int WITH_BOOK>
__global__ __launch_bounds__(256)
void ln_kernel(const float* __restrict__ x, const float* __restrict__ sc,
               const float* __restrict__ bi, u16* __restrict__ out, int ld_out,
               const int* __restrict__ ibx, const float* __restrict__ book)
{
    int row = blockIdx.x, tid = threadIdx.x;
    float4 v = reinterpret_cast<const float4*>(x + (size_t)row * D_MODEL)[tid];
    float sum = v.x + v.y + v.z + v.w;
    float sq  = v.x * v.x + v.y * v.y + v.z * v.z + v.w * v.w;
    __shared__ float red[8];
    #pragma unroll
    for (int off = 32; off > 0; off >>= 1) {
        sum += __shfl_xor(sum, off, 64);
        sq  += __shfl_xor(sq,  off, 64);
    }
    if ((tid & 63) == 0) { red[(tid >> 6) * 2] = sum; red[(tid >> 6) * 2 + 1] = sq; }
    __syncthreads();
    float tot  = red[0] + red[2] + red[4] + red[6];
    float tots = red[1] + red[3] + red[5] + red[7];
    float mu  = tot * (1.f / D_MODEL);
    float var = tots * (1.f / D_MODEL) - mu * mu;
    float rstd = rsqrtf(var + 1e-5f);
    float4 s4 = reinterpret_cast<const float4*>(sc)[tid];
    float4 b4 = reinterpret_cast<const float4*>(bi)[tid];
    u16* orow = out + (size_t)row * ld_out + tid * 4;
    orow[0] = f2bf((v.x - mu) * rstd * s4.x + b4.x);
    orow[1] = f2bf((v.y - mu) * rstd * s4.y + b4.y);
    orow[2] = f2bf((v.z - mu) * rstd * s4.z + b4.z);
    orow[3] = f2bf((v.w - mu) * rstd * s4.w + b4.w);
    if (WITH_BOOK) {
        if (tid < DB) {
            int b = row >> 10;
            out[(size_t)row * ld_out + D_MODEL + tid] = f2bf(book[ibx[b] * DB + tid]);
        }
    }
}

// ---------------------------------------------------------------------------
// GEMM: C[M,N] = A[M,K](bf16) * Bt[N,K](bf16)^T, 128x128 tile, BK=32,
// 4 waves, each 64x64 via 4x4 mfma_f32_16x16x32_bf16.
// MODE 1: -> Cb bf16, layout [b,h,t,hs]
// MODE 2: -> Cb bf16, layout [b,h,hs,t]
// MODE 3: Cf[m,n] += acc + bias[n]  (residual, in-place f32)
// MODE 4: Cb[m,n] = bf16(relu(acc + bias[n]))
// MODE 5: Cf[m,n] = acc + bias[n]
// ---------------------------------------------------------------------------
#define LDT 40  // padded LDS row stride (bf16 elems): 2-way bank alias = free

template<int MODE>
__global__ __launch_bounds__(256)
void gemm_bt(const u16* __restrict__ A, const u16* __restrict__ Bt,
             const float* __restrict__ bias, float* __restrict__ Cf,
             u16* __restrict__ Cb, int M, int N, int K)
{
    __shared__ __align__(16) u16 As[128 * LDT];
    __shared__ __align__(16) u16 Bs[128 * LDT];
    const int tid  = threadIdx.x;
    const int lane = tid & 63;
    const int widx = tid >> 6;
    const int wr = widx >> 1, wc = widx & 1;
    const int quad = lane >> 4, l15 = lane & 15;
    const int m0 = blockIdx.y * 128, n0 = blockIdx.x * 128;

    f32x4_t acc[4][4] = {};

    for (int k0 = 0; k0 < K; k0 += 32) {
        #pragma unroll
        for (int it = 0; it < 2; ++it) {
            int chunk = tid + it * 256;          // 0..511
            int row = chunk >> 2, c8 = chunk & 3;
            uint4 va = *reinterpret_cast<const uint4*>(&A [(size_t)(m0 + row) * K + k0 + c8 * 8]);
            *reinterpret_cast<uint4*>(&As[row * LDT + c8 * 8]) = va;
            uint4 vb = *reinterpret_cast<const uint4*>(&Bt[(size_t)(n0 + row) * K + k0 + c8 * 8]);
            *reinterpret_cast<uint4*>(&Bs[row * LDT + c8 * 8]) = vb;
        }
        __syncthreads();
        bf16x8_t af[4], bf[4];
        #pragma unroll
        for (int i = 0; i < 4; ++i) {
            af[i] = *reinterpret_cast<const bf16x8_t*>(&As[(wr * 64 + i * 16 + l15) * LDT + quad * 8]);
            bf[i] = *reinterpret_cast<const bf16x8_t*>(&Bs[(wc * 64 + i * 16 + l15) * LDT + quad * 8]);
        }
        #pragma unroll
        for (int i = 0; i < 4; ++i)
            #pragma unroll
            for (int j = 0; j < 4; ++j)
                acc[i][j] = __builtin_amdgcn_mfma_f32_16x16x32_bf16(af[i], bf[j], acc[i][j], 0, 0, 0);
        __syncthreads();
    }

    #pragma unroll
    for (int i = 0; i < 4; ++i) {
        #pragma unroll
        for (int j = 0; j < 4; ++j) {
            #pragma unroll
            for (int r = 0; r < 4; ++r) {
                int row = m0 + wr * 64 + i * 16 + quad * 4 + r;
                int col = n0 + wc * 64 + j * 16 + l15;
                float val = acc[i][j][r];
                if (MODE == 1) {
                    int b = row >> 10, t = row & 1023, h = col >> 6, hs = col & 63;
                    Cb[(((size_t)(b * NHEAD + h)) * T_SEQ + t) * HSZ + hs] = f2bf(val);
                } else if (MODE == 2) {
                    int b = row >> 10, t = row & 1023, h = col >> 6, hs = col & 63;
                    Cb[(((size_t)(b * NHEAD + h)) * HSZ + hs) * T_SEQ + t] = f2bf(val);
                } else if (MODE == 3) {
                    size_t o = (size_t)row * N + col;
                    Cf[o] = Cf[o] + val + bias[col];
                } else if (MODE == 4) {
                    float z = val + bias[col];
                    Cb[(size_t)row * N + col] = f2bf(z > 0.f ? z : 0.f);
                } else {
                    Cf[(size_t)row * N + col] = val + bias[col];
                }
            }
        }
    }
}

// ---------------------------------------------------------------------------
// MFMA flash attention. One block per (q-tile of 64, b*h). 4 waves, each wave
// owns 16 q rows. q,k: [b,h,t,hs] bf16; vT: [b,h,hs,t] bf16.
// Per KV tile of 64: S = mfma(Q,K) -> online softmax in regs -> P via LDS
// relayout -> O += mfma(P, vT). Writes o to [b,t,d] bf16.
// ---------------------------------------------------------------------------
#define ALDP 72   // padded LDS stride (bf16): 16B-aligned, breaks 128B bank wrap

__global__ __launch_bounds__(256)
void attn_mfma(const u16* __restrict__ qb, const u16* __restrict__ kb,
               const u16* __restrict__ vtb, u16* __restrict__ ob)
{
    __shared__ __align__(16) u16 Ks[64 * ALDP];
    __shared__ __align__(16) u16 Vs[64 * ALDP];           // vT tile: [d][s]
    __shared__ __align__(16) u16 Ps[4][16 * ALDP];        // per-wave P

    const int tid  = threadIdx.x;
    const int lane = tid & 63;
    const int wq   = tid >> 6;                 // wave -> q sub-tile
    const int quad = lane >> 4, l15 = lane & 15;
    const int qt   = blockIdx.x;
    const int q0   = qt * 64;
    const int bh   = blockIdx.y;

    const u16* qg = qb  + (size_t)bh * T_SEQ * HSZ;   // [t][hs]
    const u16* kg = kb  + (size_t)bh * T_SEQ * HSZ;   // [t][hs]
    const u16* vg = vtb + (size_t)bh * HSZ * T_SEQ;   // [d][t]

    // Q fragments for the whole kernel (A layout: row=l15, k=quad*8+e)
    bf16x8_t aq[2];
    {
        const int qrow = q0 + wq * 16 + l15;
        aq[0] = *reinterpret_cast<const bf16x8_t*>(&qg[(size_t)qrow * HSZ + quad * 8]);
        aq[1] = *reinterpret_cast<const bf16x8_t*>(&qg[(size_t)qrow * HSZ + 32 + quad * 8]);
    }

    f32x4_t acc_o[4] = {};
    float m_run[4] = { -1e30f, -1e30f, -1e30f, -1e30f };
    float l_run[4] = { 0.f, 0.f, 0.f, 0.f };

    const int row0 = tid >> 3;   // staging: rows 0..31 (and +32)
    const int c8   = tid & 7;    // 8-bf16 chunk within a 64-wide row

    for (int ti = 0; ti <= qt; ++ti) {
        const int s0 = ti * 64;
        // issue global loads early: HBM latency hides under prev tile's MFMAs
        uint4 kv0 = *reinterpret_cast<const uint4*>(&kg[(size_t)(s0 + row0) * HSZ + c8 * 8]);
        uint4 kv1 = *reinterpret_cast<const uint4*>(&kg[(size_t)(s0 + row0 + 32) * HSZ + c8 * 8]);
        uint4 vv0 = *reinterpret_cast<const uint4*>(&vg[(size_t)row0 * T_SEQ + s0 + c8 * 8]);
        uint4 vv1 = *reinterpret_cast<const uint4*>(&vg[(size_t)(row0 + 32) * T_SEQ + s0 + c8 * 8]);
        __syncthreads();   // prior tile's LDS reads done
        *reinterpret_cast<uint4*>(&Ks[ row0       * ALDP + c8 * 8]) = kv0;
        *reinterpret_cast<uint4*>(&Ks[(row0 + 32) * ALDP + c8 * 8]) = kv1;
        *reinterpret_cast<uint4*>(&Vs[ row0       * ALDP + c8 * 8]) = vv0;
        *reinterpret_cast<uint4*>(&Vs[(row0 + 32) * ALDP + c8 * 8]) = vv1;
        __syncthreads();

        // S = Q * K^T  (rows: q, cols: s)
        f32x4_t sa[4] = {};
        #pragma unroll
        for (int j = 0; j < 4; ++j) {
            #pragma unroll
            for (int c = 0; c < 2; ++c) {
                bf16x8_t bk = *reinterpret_cast<const bf16x8_t*>(
                    &Ks[(j * 16 + l15) * ALDP + c * 32 + quad * 8]);
                sa[j] = __builtin_amdgcn_mfma_f32_16x16x32_bf16(aq[c], bk, sa[j], 0, 0, 0);
            }
        }

        // online softmax; C layout: row = quad*4 + r, col = j*16 + l15
        const bool diag = (ti == qt);
        float pw[4][4];
        #pragma unroll
        for (int r = 0; r < 4; ++r) {
            const int q_idx = q0 + wq * 16 + quad * 4 + r;
            float mc = -1e30f;
            #pragma unroll
            for (int j = 0; j < 4; ++j) {
                float x = sa[j][r] * 0.125f;    // 64^-0.5
                if (diag && (s0 + j * 16 + l15 > q_idx)) x = -1e30f;
                sa[j][r] = x;
                mc = fmaxf(mc, x);
            }
            #pragma unroll
            for (int off = 1; off < 16; off <<= 1) mc = fmaxf(mc, __shfl_xor(mc, off, 64));
            const float m_new = fmaxf(m_run[r], mc);
            const float alpha = __expf(m_run[r] - m_new);
            m_run[r] = m_new;
            float ps = 0.f;
            #pragma unroll
            for (int j = 0; j < 4; ++j) {
                float p = __expf(sa[j][r] - m_new);
                pw[j][r] = p;
                ps += p;
            }
            #pragma unroll
            for (int off = 1; off < 16; off <<= 1) ps += __shfl_xor(ps, off, 64);
            l_run[r] = l_run[r] * alpha + ps;
            #pragma unroll
            for (int j2 = 0; j2 < 4; ++j2) acc_o[j2][r] *= alpha;
        }

        // P -> LDS (relayout to A-fragment order), per-wave region
        #pragma unroll
        for (int r = 0; r < 4; ++r)
            #pragma unroll
            for (int j = 0; j < 4; ++j)
                Ps[wq][(quad * 4 + r) * ALDP + j * 16 + l15] = f2bf(pw[j][r]);
        asm volatile("s_waitcnt lgkmcnt(0)" ::: "memory");
        __builtin_amdgcn_sched_barrier(0);

        // O += P * V   (A: P rows=q; B^T: vT rows=d)
        #pragma unroll
        for (int c2 = 0; c2 < 2; ++c2) {
            bf16x8_t ap = *reinterpret_cast<const bf16x8_t*>(
                &Ps[wq][l15 * ALDP + c2 * 32 + quad * 8]);
            #pragma unroll
            for (int j2 = 0; j2 < 4; ++j2) {
                bf16x8_t bv = *reinterpret_cast<const bf16x8_t*>(
                    &Vs[(j2 * 16 + l15) * ALDP + c2 * 32 + quad * 8]);
                acc_o[j2] = __builtin_amdgcn_mfma_f32_16x16x32_bf16(ap, bv, acc_o[j2], 0, 0, 0);
            }
        }
    }

    const int b = bh >> 4, h = bh & (NHEAD - 1);
    #pragma unroll
    for (int r = 0; r < 4; ++r) {
        const int qrow = q0 + wq * 16 + quad * 4 + r;
        const float inv = 1.f / l_run[r];
        u16* orow = ob + ((size_t)(b * T_SEQ + qrow)) * D_MODEL + h * HSZ;
        #pragma unroll
        for (int j2 = 0; j2 < 4; ++j2)
            orow[j2 * 16 + l15] = f2bf(acc_o[j2][r] * inv);
    }
}

// ---------------------------------------------------------------------------
// Loss: per row log-softmax over 32000 logits; atomicAdd mean NLL.
// ---------------------------------------------------------------------------
__global__ __launch_bounds__(256)
void loss_kernel(const float* __restrict__ logits, const int* __restrict__ targets,
                 float* __restrict__ loss)
{
    int row = blockIdx.x, tid = threadIdx.x;
    const float* lr = logits + (size_t)row * VOCAB;
    __shared__ float redm[4], reds[4];
    float m = -1e30f;
    for (int i = tid; i < VOCAB; i += 256) m = fmaxf(m, lr[i]);
    #pragma unroll
    for (int off = 32; off > 0; off >>= 1) m = fmaxf(m, __shfl_xor(m, off, 64));
    if ((tid & 63) == 0) redm[tid >> 6] = m;
    __syncthreads();
    m = fmaxf(fmaxf(redm[0], redm[1]), fmaxf(redm[2], redm[3]));
    float s = 0.f;
    for (int i = tid; i < VOCAB; i += 256) s += __expf(lr[i] - m);
    #pragma unroll
    for (int off = 32; off > 0; off >>= 1) s += __shfl_xor(s, off, 64);
    if ((tid & 63) == 0) reds[tid >> 6] = s;
    __syncthreads();
    if (tid == 0) {
        float tot = reds[0] + reds[1] + reds[2] + reds[3];
        float lse = m + logf(tot);
        atomicAdd(loss, (lse - lr[targets[row]]) * (1.f / NROWS));
    }
}

// ---------------------------------------------------------------------------
extern "C" void kernel_launch(void* const* d_in, const int* in_sizes, int n_in,
                              void* d_out, int out_size, void* d_ws, size_t ws_size,
                              hipStream_t stream)
{
    (void)in_sizes; (void)n_in; (void)out_size; (void)ws_size;
    const int*   idx    = (const int*)d_in[0];
    const int*   ibx    = (const int*)d_in[1];
    const int*   targ   = (const int*)d_in[2];
    const float* tok    = (const float*)d_in[3];
    const float* pos    = (const float*)d_in[4];
    const float* book   = (const float*)d_in[5];
    const float* Wq     = (const float*)d_in[6];
    const float* Wk     = (const float*)d_in[7];
    const float* Wv     = (const float*)d_in[8];
    const float* Wo     = (const float*)d_in[9];
    const float* bo     = (const float*)d_in[10];
    const float* ln1_s  = (const float*)d_in[11];
    const float* ln1_b  = (const float*)d_in[12];
    const float* ln2_s  = (const float*)d_in[13];
    const float* ln2_b  = (const float*)d_in[14];
    const float* W1     = (const float*)d_in[15];
    const float* b1     = (const float*)d_in[16];
    const float* W2     = (const float*)d_in[17];
    const float* b2     = (const float*)d_in[18];
    const float* lnf_s  = (const float*)d_in[19];
    const float* lnf_b  = (const float*)d_in[20];
    const float* Wh     = (const float*)d_in[21];
    const float* bh     = (const float*)d_in[22];
    float* out    = (float*)d_out;
    float* d_loss = out + (size_t)NROWS * VOCAB;

    char* w = (char*)d_ws;
    size_t off = 0;
    auto alloc = [&](size_t bytes) -> char* {
        char* p = w + off; off += (bytes + 255) & ~(size_t)255; return p;
    };
    float* xw  = (float*)alloc((size_t)NROWS * D_MODEL * 4);
    u16* hb    = (u16*)alloc((size_t)NROWS * D_MODEL * 2);
    u16* qb    = (u16*)alloc((size_t)NROWS * D_MODEL * 2);
    u16* kbuf  = (u16*)alloc((size_t)NROWS * D_MODEL * 2);
    u16* vtb   = (u16*)alloc((size_t)NROWS * D_MODEL * 2);
    u16* obuf  = (u16*)alloc((size_t)NROWS * D_MODEL * 2);
    u16* h2b   = (u16*)alloc((size_t)NROWS * DCAT * 2);
    u16* ffb   = (u16*)alloc((size_t)NROWS * DFF * 2);
    u16* wqt   = (u16*)alloc((size_t)NLAYER * D_MODEL * D_MODEL * 2);
    u16* wkt   = (u16*)alloc((size_t)NLAYER * D_MODEL * D_MODEL * 2);
    u16* wvt   = (u16*)alloc((size_t)NLAYER * D_MODEL * D_MODEL * 2);
    u16* wot   = (u16*)alloc((size_t)NLAYER * D_MODEL * D_MODEL * 2);
    u16* w1t   = (u16*)alloc((size_t)NLAYER * DCAT * DFF * 2);
    u16* w2t   = (u16*)alloc((size_t)NLAYER * DFF * D_MODEL * 2);
    u16* wht   = (u16*)alloc((size_t)D_MODEL * VOCAB * 2);

    // Weight transposes (f32 [K,N] -> bf16 [N,K])
    transpose_cvt<<<dim3(32, 32, 6), 256, 0, stream>>>(Wq, wqt, D_MODEL, D_MODEL);
    transpose_cvt<<<dim3(32, 32, 6), 256, 0, stream>>>(Wk, wkt, D_MODEL, D_MODEL);
    transpose_cvt<<<dim3(32, 32, 6), 256, 0, stream>>>(Wv, wvt, D_MODEL, D_MODEL);
    transpose_cvt<<<dim3(32, 32, 6), 256, 0, stream>>>(Wo, wot, D_MODEL, D_MODEL);
    transpose_cvt<<<dim3(DFF / 32, DCAT / 32, 6), 256, 0, stream>>>(W1, w1t, DCAT, DFF);
    transpose_cvt<<<dim3(D_MODEL / 32, DFF / 32, 6), 256, 0, stream>>>(W2, w2t, DFF, D_MODEL);
    transpose_cvt<<<dim3(VOCAB / 32, D_MODEL / 32, 1), 256, 0, stream>>>(Wh, wht, D_MODEL, VOCAB);

    embed_kernel<<<NROWS, 256, 0, stream>>>(idx, tok, pos, xw, d_loss);

    for (int l = 0; l < NLAYER; ++l) {
        size_t wo2 = (size_t)l * D_MODEL * D_MODEL;
        ln_kernel<0><<<NROWS, 256, 0, stream>>>(xw, ln1_s + l * D_MODEL, ln1_b + l * D_MODEL,
                                                hb, D_MODEL, nullptr, nullptr);
        gemm_bt<1><<<dim3(8, 32), 256, 0, stream>>>(hb, wqt + wo2, nullptr, nullptr, qb,
                                                    NROWS, D_MODEL, D_MODEL);
        gemm_bt<1><<<dim3(8, 32), 256, 0, stream>>>(hb, wkt + wo2, nullptr, nullptr, kbuf,
                                                    NROWS, D_MODEL, D_MODEL);
        gemm_bt<2><<<dim3(8, 32), 256, 0, stream>>>(hb, wvt + wo2, nullptr, nullptr, vtb,
                                                    NROWS, D_MODEL, D_MODEL);
        attn_mfma<<<dim3(T_SEQ / 64, BATCH * NHEAD), 256, 0, stream>>>(qb, kbuf, vtb, obuf);
        gemm_bt<3><<<dim3(8, 32), 256, 0, stream>>>(obuf, wot + wo2, bo + l * D_MODEL, xw, nullptr,
                                                    NROWS, D_MODEL, D_MODEL);
        ln_kernel<1><<<NROWS, 256, 0, stream>>>(xw, ln2_s + l * D_MODEL, ln2_b + l * D_MODEL,
                                                h2b, DCAT, ibx, book);
        gemm_bt<4><<<dim3(DFF / 128, 32), 256, 0, stream>>>(h2b, w1t + (size_t)l * DCAT * DFF,
                                                            b1 + l * DFF, nullptr, ffb,
                                                            NROWS, DFF, DCAT);
        gemm_bt<3><<<dim3(8, 32), 256, 0, stream>>>(ffb, w2t + (size_t)l * DFF * D_MODEL,
                                                    b2 + l * D_MODEL, xw, nullptr,
                                                    NROWS, D_MODEL, DFF);
    }

    ln_kernel<0><<<NROWS, 256, 0, stream>>>(xw, lnf_s, lnf_b, hb, D_MODEL, nullptr, nullptr);
    gemm_bt<5><<<dim3(VOCAB / 128, 32), 256, 0, stream>>>(hb, wht, bh, out, nullptr,
                                                          NROWS, VOCAB, D_MODEL);
    loss_kernel<<<NROWS, 256, 0, stream>>>(out, targ, d_loss);
}